// Round 3
// baseline (592.740 us; speedup 1.0000x reference)
//
#include <hip/hip_runtime.h>
#include <math.h>

// Problem constants (fixed by reference)
#define BS_TOT 32768      // B*S = 16*2048
#define IN_DIM 768
#define G_N 2
#define V_N 320
#define D_N 384
#define OUT_N 768
#define EPS_F 1e-10f

typedef _Float16 f16x8 __attribute__((ext_vector_type(8)));
typedef float    f32x16 __attribute__((ext_vector_type(16)));

#define GLOBAL_LOAD_LDS16(gaddr, laddr)                                        \
  __builtin_amdgcn_global_load_lds(                                            \
      (const __attribute__((address_space(1))) unsigned int*)(gaddr),          \
      (__attribute__((address_space(3))) unsigned int*)(laddr), 16, 0, 0)

// ---------------------------------------------------------------------------
// Kernel 0: split W_logits [384][320] fp32 into two f16 planes, tiled per
// K=16 chunk for direct global_load_lds staging:
//   unit index = ((kt2*2 + pl)*2 + kh)*320 + v   (f16x8 units)
// where k = kt2*16 + kh*8 + j. pl0 = f16(w); pl1 = f16(4096*(w - pl0)).
// ---------------------------------------------------------------------------
__global__ __launch_bounds__(256) void prep_w(
    const float* __restrict__ Wl, _Float16* __restrict__ Wp)
{
    int e = blockIdx.x * 256 + threadIdx.x;
    if (e >= D_N * V_N) return;
    int k = e / V_N, v = e - k * V_N;
    int kt2 = k >> 4, kh = (k >> 3) & 1, j = k & 7;
    float w = Wl[e];
    _Float16 a = (_Float16)w;
    float r = (w - (float)a) * 4096.f;
    Wp[((size_t)(((kt2 * 2 + 0) * 2 + kh) * V_N) + v) * 8 + j] = a;
    Wp[((size_t)(((kt2 * 2 + 1) * 2 + kh) * V_N) + v) * 8 + j] = (_Float16)r;
}

// ---------------------------------------------------------------------------
// Kernel A: P[g*320+v][o] = sum_d codebooks[g][v][d] * W_out[g*384+d][o]
// (validated in R1)
// ---------------------------------------------------------------------------
__global__ __launch_bounds__(256) void precompute_P(
    const float* __restrict__ cb, const float* __restrict__ Wo,
    float* __restrict__ P)
{
    const int tid = threadIdx.x;
    const int c0  = blockIdx.x * 256;
    const int r0  = blockIdx.y * 8;
    const int g   = r0 / V_N;
    __shared__ float As[8][D_N];
    {
        const float4* src = (const float4*)(cb + (size_t)r0 * D_N);
        float4* dst = (float4*)(&As[0][0]);
        #pragma unroll
        for (int p = 0; p < 3; ++p) dst[tid + p * 256] = src[tid + p * 256];
    }
    __syncthreads();
    float acc[8];
    #pragma unroll
    for (int i = 0; i < 8; ++i) acc[i] = 0.f;
    const float* wp = Wo + ((size_t)g * D_N) * OUT_N + c0 + tid;
    for (int d = 0; d < D_N; d += 4) {
        float w0 = wp[(size_t)(d + 0) * OUT_N];
        float w1 = wp[(size_t)(d + 1) * OUT_N];
        float w2 = wp[(size_t)(d + 2) * OUT_N];
        float w3 = wp[(size_t)(d + 3) * OUT_N];
        #pragma unroll
        for (int i = 0; i < 8; ++i) {
            float4 a = *(const float4*)&As[i][d];
            acc[i] = fmaf(a.x, w0, acc[i]);
            acc[i] = fmaf(a.y, w1, acc[i]);
            acc[i] = fmaf(a.z, w2, acc[i]);
            acc[i] = fmaf(a.w, w3, acc[i]);
        }
    }
    #pragma unroll
    for (int i = 0; i < 8; ++i)
        P[(size_t)(r0 + i) * OUT_N + c0 + tid] = acc[i];
}

// ---------------------------------------------------------------------------
// Kernel B: split-f16 MFMA logits GEMM + gumbel + argmax.
// BM=128, BN=320 (full), BK=16, 24 K-iters. Block 256 = 4 waves, wave tile
// 64x160: 2 M-frags x 5 N-frags x 2 acc sets = 320 acc VGPRs, 1 wave/SIMD.
// Issue-early double-buffered staging: DMA for tile t+1 issued at top of
// compute(t), drained by the single barrier at end of iter t (full compute
// phase in flight, no lockstep drain). z pipelined 2-deep in registers.
// Numerics identical to R2's validated kernel.
// ---------------------------------------------------------------------------
__global__ __launch_bounds__(256, 1) void logits_mfma(
    const float* __restrict__ z, const float* __restrict__ noise,
    const f16x8* __restrict__ Wp, const float* __restrict__ bl,
    int* __restrict__ idx)
{
    const int tid  = threadIdx.x;
    const int g    = blockIdx.y;
    const int m0   = blockIdx.x * 128;
    const int ln   = tid & 63;
    const int wv   = tid >> 6;
    const int wrow = wv >> 1;      // 0..1: 64-row half
    const int wcol = wv & 1;       // 0..1: 160-col half
    const int lh   = ln >> 5;
    const int l5   = ln & 31;

    __shared__ f16x8 Bs[2][1280];  // [(pl*2+kh)*320 + v], 2x20 KB
    __shared__ f16x8 As[2][512];   // [(pl*2+kh)*128 + row], 2x8 KB
    __shared__ float sVal[2][128];
    __shared__ int   sIdx[2][128];

    f32x16 accM[2][5], accC[2][5];
    #pragma unroll
    for (int mf = 0; mf < 2; ++mf)
        #pragma unroll
        for (int nf = 0; nf < 5; ++nf)
            #pragma unroll
            for (int i = 0; i < 16; ++i) { accM[mf][nf][i] = 0.f; accC[mf][nf][i] = 0.f; }

    // A staging map: thread t stages row (t&127), k-octet (t>>7) of each tile
    const int ar = tid & 127;
    const int ah = tid >> 7;
    const float* zrow = z + (size_t)(m0 + ar) * IN_DIM + g * D_N + ah * 8;

    // ---- prime: tile 0 into buffer 0; z tile 1 into regs ----
    #pragma unroll
    for (int q = 0; q < 5; ++q)
        GLOBAL_LOAD_LDS16(Wp + wv * 320 + q * 64 + ln, &Bs[0][wv * 320 + q * 64]);
    {
        float4 c0 = *(const float4*)zrow;
        float4 c1 = *(const float4*)(zrow + 4);
        float x[8] = {c0.x, c0.y, c0.z, c0.w, c1.x, c1.y, c1.z, c1.w};
        f16x8 h1, h2;
        #pragma unroll
        for (int i = 0; i < 8; ++i) {
            _Float16 a = (_Float16)x[i];
            h1[i] = a;
            h2[i] = (_Float16)((x[i] - (float)a) * 4096.f);
        }
        As[0][(0 + ah) * 128 + ar] = h1;
        As[0][(2 + ah) * 128 + ar] = h2;
    }
    float4 n0 = *(const float4*)(zrow + 16);
    float4 n1 = *(const float4*)(zrow + 20);
    __syncthreads();

    const int arow0 = wrow * 64 + l5;        // mf=0 frag row
    const int bc    = wcol * 160 + l5;       // frag col base

    for (int kt = 0; kt < 24; ++kt) {
        const int p = kt & 1;
        // issue-early: stage tile kt+1 into the other buffer (drains at the
        // barrier at the END of this iteration — full compute phase in flight)
        if (kt < 23) {
            #pragma unroll
            for (int q = 0; q < 5; ++q)
                GLOBAL_LOAD_LDS16(Wp + (size_t)(kt + 1) * 1280 + wv * 320 + q * 64 + ln,
                                  &Bs[1 - p][wv * 320 + q * 64]);
            float x[8] = {n0.x, n0.y, n0.z, n0.w, n1.x, n1.y, n1.z, n1.w};
            f16x8 h1, h2;
            #pragma unroll
            for (int i = 0; i < 8; ++i) {
                _Float16 a = (_Float16)x[i];
                h1[i] = a;
                h2[i] = (_Float16)((x[i] - (float)a) * 4096.f);
            }
            As[1 - p][(0 + ah) * 128 + ar] = h1;
            As[1 - p][(2 + ah) * 128 + ar] = h2;
        }
        if (kt < 22) {   // z 2-deep register pipeline
            n0 = *(const float4*)(zrow + (kt + 2) * 16);
            n1 = *(const float4*)(zrow + (kt + 2) * 16 + 4);
        }
        // compute tile kt from buffer p: a-frags hoisted, 14 LDS reads / 30 MFMA
        {
            f16x8 a00 = As[p][(0 + lh) * 128 + arow0];
            f16x8 a01 = As[p][(2 + lh) * 128 + arow0];
            f16x8 a10 = As[p][(0 + lh) * 128 + arow0 + 32];
            f16x8 a11 = As[p][(2 + lh) * 128 + arow0 + 32];
            #pragma unroll
            for (int nf = 0; nf < 5; ++nf) {
                f16x8 b0 = Bs[p][(0 + lh) * 320 + bc + nf * 32];
                f16x8 b1 = Bs[p][(2 + lh) * 320 + bc + nf * 32];
                accM[0][nf] = __builtin_amdgcn_mfma_f32_32x32x16_f16(a00, b0, accM[0][nf], 0, 0, 0);
                accC[0][nf] = __builtin_amdgcn_mfma_f32_32x32x16_f16(a00, b1, accC[0][nf], 0, 0, 0);
                accC[0][nf] = __builtin_amdgcn_mfma_f32_32x32x16_f16(a01, b0, accC[0][nf], 0, 0, 0);
                accM[1][nf] = __builtin_amdgcn_mfma_f32_32x32x16_f16(a10, b0, accM[1][nf], 0, 0, 0);
                accC[1][nf] = __builtin_amdgcn_mfma_f32_32x32x16_f16(a10, b1, accC[1][nf], 0, 0, 0);
                accC[1][nf] = __builtin_amdgcn_mfma_f32_32x32x16_f16(a11, b0, accC[1][nf], 0, 0, 0);
            }
        }
        __syncthreads();
    }

    // ---- epilogue: logits = main + 2^-12*cross + bl + gumbel; argmax ----
    float blv[5];
    #pragma unroll
    for (int nf = 0; nf < 5; ++nf) blv[nf] = bl[wcol * 160 + nf * 32 + l5];

    #pragma unroll
    for (int mf = 0; mf < 2; ++mf) {
        #pragma unroll
        for (int r = 0; r < 16; ++r) {
            const int rowloc = (r & 3) + 8 * (r >> 2) + 4 * lh;   // C/D row map
            const int growb  = wrow * 64 + mf * 32 + rowloc;      // block-local row
            const int grow   = m0 + growb;
            const float* nrow = noise + ((size_t)grow * G_N + g) * V_N + wcol * 160 + l5;
            float best = -INFINITY; int bi = 0;
            #pragma unroll
            for (int nf = 0; nf < 5; ++nf) {
                float u   = nrow[nf * 32];
                float gum = -__logf(-__logf(u + EPS_F) + EPS_F);
                float v   = accM[mf][nf][r] + 2.44140625e-4f * accC[mf][nf][r]
                            + blv[nf] + gum;
                int   c   = wcol * 160 + nf * 32 + l5;
                if (v > best) { best = v; bi = c; }
            }
            #pragma unroll
            for (int off = 1; off < 32; off <<= 1) {   // reduce within 32-lane half
                float ov = __shfl_xor(best, off);
                int   oi = __shfl_xor(bi, off);
                if (ov > best || (ov == best && oi < bi)) { best = ov; bi = oi; }
            }
            if (l5 == 0) {
                sVal[wcol][growb] = best;
                sIdx[wcol][growb] = bi;
            }
        }
    }
    __syncthreads();
    if (tid < 128) {
        float v0 = sVal[0][tid], v1 = sVal[1][tid];
        int   i0 = sIdx[0][tid], i1 = sIdx[1][tid];
        int   b  = (v1 > v0 || (v1 == v0 && i1 < i0)) ? i1 : i0;
        idx[(size_t)(m0 + tid) * G_N + g] = b;
    }
}

// ---------------------------------------------------------------------------
// Kernel C: out[row] = P[idx0[row]] + P[320 + idx1[row]] + b_out
// (validated in R1, write-bound)
// ---------------------------------------------------------------------------
__global__ __launch_bounds__(256) void gather_out(
    const float* __restrict__ P, const int* __restrict__ idx,
    const float* __restrict__ bo, float* __restrict__ out)
{
    const int tid  = threadIdx.x;
    const int row0 = blockIdx.x << 2;
    #pragma unroll
    for (int p = 0; p < 3; ++p) {
        int f   = tid + (p << 8);
        int rl  = f / 192;
        int c4  = f - rl * 192;
        int row = row0 + rl;
        int i0  = idx[row * 2];
        int i1  = idx[row * 2 + 1];
        float4 a  = ((const float4*)(P + (size_t)i0 * OUT_N))[c4];
        float4 b2 = ((const float4*)(P + (size_t)(V_N + i1) * OUT_N))[c4];
        float4 c  = ((const float4*)bo)[c4];
        float4 r;
        r.x = a.x + b2.x + c.x;
        r.y = a.y + b2.y + c.y;
        r.z = a.z + b2.z + c.z;
        r.w = a.w + b2.w + c.w;
        ((float4*)(out + (size_t)row * OUT_N))[c4] = r;
    }
}

// ---------------------------------------------------------------------------
extern "C" void kernel_launch(void* const* d_in, const int* in_sizes, int n_in,
                              void* d_out, int out_size, void* d_ws, size_t ws_size,
                              hipStream_t stream)
{
    const float* z     = (const float*)d_in[0];
    const float* noise = (const float*)d_in[1];
    const float* Wl    = (const float*)d_in[2];
    const float* bl    = (const float*)d_in[3];
    const float* cb    = (const float*)d_in[4];
    const float* Wo    = (const float*)d_in[5];
    const float* bo    = (const float*)d_in[6];
    float* out = (float*)d_out;

    // ws layout: P (1,966,080 B) | idx (262,144 B) | Wp f16 planes (491,520 B)
    float*     P   = (float*)d_ws;
    int*       idx = (int*)((char*)d_ws + 1966080);
    _Float16*  Wp  = (_Float16*)((char*)d_ws + 2228224);

    prep_w<<<(D_N * V_N + 255) / 256, 256, 0, stream>>>(Wl, Wp);

    dim3 gA(OUT_N / 256, (G_N * V_N) / 8);
    precompute_P<<<gA, 256, 0, stream>>>(cb, Wo, P);

    dim3 gB(BS_TOT / 128, G_N);
    logits_mfma<<<gB, 256, 0, stream>>>(z, noise, (const f16x8*)Wp, bl, idx);

    gather_out<<<BS_TOT / 4, 256, 0, stream>>>(P, idx, bo, out);
}